// Round 11
// baseline (190.838 us; speedup 1.0000x reference)
//
#include <hip/hip_runtime.h>
#include <hip/hip_bf16.h>

#define Bn 8
#define Nn 1024
#define Dn 256
#define Hn 4
#define HOn 64
#define Tn 5
#define WTR 80   // WT rows per head: 64 W^T cols + 10 Wa rows + 6 zero pad

typedef short bf16x8 __attribute__((ext_vector_type(8)));
typedef float f32x4 __attribute__((ext_vector_type(4)));

__device__ __forceinline__ float b2f(unsigned short u) {
    unsigned x = ((unsigned)u) << 16;
    float f;
    __builtin_memcpy(&f, &x, 4);
    return f;
}
// fast RNE f32->bf16 (finite inputs only)
__device__ __forceinline__ unsigned bfr(float f) {
    unsigned u;
    __builtin_memcpy(&u, &f, 4);
    return (u + 0x7FFFu + ((u >> 16) & 1u)) >> 16;
}
__device__ __forceinline__ unsigned short f2b(float f) { return (unsigned short)bfr(f); }

// ---------- fallback: signal "workspace too small" with out = 100.0 ----------
__global__ __launch_bounds__(256) void k_signal(float* __restrict__ out, int n) {
    int i = blockIdx.x * 256 + threadIdx.x;
    if (i < n) out[i] = 100.0f;
}

// ---------- kernel 0: WT [H][80][D] bf16: rows 0-63 = W^T, 64-73 = W.a_src|W.a_dst, 74-79 = 0
__global__ __launch_bounds__(256) void k_transpose_w(const float* __restrict__ W,
                                                     const float* __restrict__ a_src,
                                                     const float* __restrict__ a_dst,
                                                     unsigned short* __restrict__ WT) {
    __shared__ float tile[64][65];
    int h = blockIdx.x >> 2;
    int d0 = (blockIdx.x & 3) * 64;
    int c0 = threadIdx.x & 63;
    int r0 = threadIdx.x >> 6;  // 0..3
#pragma unroll
    for (int r = 0; r < 16; r++) {
        int d = r * 4 + r0;
        tile[d][c0] = W[((size_t)(h * Dn + d0 + d)) * HOn + c0];  // coalesced over e
    }
    __syncthreads();
#pragma unroll
    for (int r = 0; r < 16; r++) {
        int e = r * 4 + r0;
        WT[((size_t)(h * WTR + e)) * Dn + d0 + c0] = f2b(tile[c0][e]);
    }
    for (int t = r0; t < 2 * Tn; t += 4) {
        const float* av = (t < Tn) ? (a_src + (h * Tn + t) * HOn)
                                   : (a_dst + (h * Tn + t - Tn) * HOn);
        float s = 0.f;
#pragma unroll
        for (int e = 0; e < HOn; e++) s += tile[c0][e] * av[e];
        WT[((size_t)(h * WTR + 64 + t)) * Dn + d0 + c0] = f2b(s);
    }
    for (int rr = 74 + r0; rr < WTR; rr += 4)
        WT[((size_t)(h * WTR + rr)) * Dn + d0 + c0] = 0;
}

// ---------- kernel 1: h^T = W^T x X^T via MFMA (A = W^T so C/D col = i -> coalesced stores)
// grid: B * (N/16) blocks x 256 threads; wave w = head w.
__global__ __launch_bounds__(256) void k_proj(const float* __restrict__ X,
                                              const unsigned short* __restrict__ WT,
                                              unsigned short* __restrict__ hT,
                                              float* __restrict__ e_src,
                                              float* __restrict__ e_dst) {
    int tid = threadIdx.x;
    int w = tid >> 6;
    int lane = tid & 63;
    int quad = lane >> 4;
    int l15 = lane & 15;
    int b = blockIdx.x >> 6;
    int i0 = (blockIdx.x & 63) * 16;
    int h = w;
    int bh = b * Hn + h;

    // B-frag: B[k=quad*8+idx (=d)][n=l15 (=i)] <- X rows, f32 -> bf16 via cvt_pk
    bf16x8 Bx[8];
    const float* xf = X + ((size_t)(b * Nn + i0 + l15)) * Dn + quad * 8;
#pragma unroll
    for (int kc = 0; kc < 8; kc++) {
        union { bf16x8 v; unsigned u[4]; } uu;
        const float4* xp = (const float4*)(xf + kc * 32);
        float4 A0 = xp[0], A1 = xp[1];
        __hip_bfloat162 h0 = __float22bfloat162_rn(make_float2(A0.x, A0.y));
        __hip_bfloat162 h1 = __float22bfloat162_rn(make_float2(A0.z, A0.w));
        __hip_bfloat162 h2 = __float22bfloat162_rn(make_float2(A1.x, A1.y));
        __hip_bfloat162 h3 = __float22bfloat162_rn(make_float2(A1.z, A1.w));
        __builtin_memcpy(&uu.u[0], &h0, 4);
        __builtin_memcpy(&uu.u[1], &h1, 4);
        __builtin_memcpy(&uu.u[2], &h2, 4);
        __builtin_memcpy(&uu.u[3], &h3, 4);
        Bx[kc] = uu.v;
    }

    f32x4 acc[5] = {{0.f, 0.f, 0.f, 0.f}, {0.f, 0.f, 0.f, 0.f}, {0.f, 0.f, 0.f, 0.f},
                    {0.f, 0.f, 0.f, 0.f}, {0.f, 0.f, 0.f, 0.f}};
    const unsigned short* wbase = WT + (size_t)h * WTR * Dn;
#pragma unroll
    for (int kc = 0; kc < 8; kc++) {
#pragma unroll
        for (int et = 0; et < 5; et++) {
            // A-frag: A[m=l15 (=e-in-16)][k=quad*8+idx (=d)] <- WT rows
            bf16x8 Aw = *(const bf16x8*)(wbase + (size_t)(et * 16 + l15) * Dn + kc * 32 + quad * 8);
            acc[et] = __builtin_amdgcn_mfma_f32_16x16x32_bf16(Aw, Bx[kc], acc[et], 0, 0, 0);
        }
    }

    // C/D: col=l15 -> i, row=quad*4+reg -> m. hT stores: 16 lanes x 2B contiguous per (et,quad,reg)
#pragma unroll
    for (int et = 0; et < 4; et++) {
#pragma unroll
        for (int reg = 0; reg < 4; reg++) {
            int e = et * 16 + quad * 4 + reg;
            hT[((size_t)bh * HOn + e) * Nn + i0 + l15] = f2b(acc[et][reg]);
        }
    }
    // 5th tile rows: t = quad*4+reg (0-4: e_src, 5-9: e_dst, 10-15: pad)
#pragma unroll
    for (int reg = 0; reg < 4; reg++) {
        int t = quad * 4 + reg;
        if (t < Tn)
            e_src[((size_t)bh * Tn + t) * Nn + i0 + l15] = acc[4][reg];
        else if (t < 2 * Tn)
            e_dst[((size_t)bh * Tn + (t - Tn)) * Nn + i0 + l15] = acc[4][reg];
    }
}

// ---------- kernel 2: fused attention; 8-row i-tiles for full occupancy ----------
// grid: B * (N/8) = 1024 blocks x 512 threads (8 waves); wave = (head = w&3, j-half = w>>2).
// 4 blocks/CU (threads + 35.8 KB LDS) -> 32 waves/CU. MFMA runs half-empty (rows 8-15
// zero/discarded) — MfmaUtil was 2.6%, the waste is cheap; TLP doubling is the win.
// NOTE: no min-waves (R7 spill); chunk loop rolled (R8 spill); register selects not LDS
// tables (R10: data-dependent LDS gathers cost 6.1M bank-conflict cycles).
__global__ __launch_bounds__(512) void k_attn(const int* __restrict__ adj,
                                              const float* __restrict__ e_src,
                                              const float* __restrict__ e_dst,
                                              const unsigned short* __restrict__ hT,
                                              const float* __restrict__ bias,
                                              const float* __restrict__ gamma,
                                              const float* __restrict__ beta,
                                              float* __restrict__ out) {
    // p_lds rows 0-7 = P (8 real rows); rows 8-15 zeroed once (A-frag hygiene).
    // After the chunk loop waves 4-7's p regions are dead; macc (8 KB) overlays p_lds[4..].
    __shared__ __align__(16) unsigned short p_lds[8][16][136];  // 34,816 B
    __shared__ float es_lds[4][Tn][8];                          // 640 B
    __shared__ float l_lds[8][8];                               // 256 B
    float* macc = (float*)&p_lds[4][0][0];  // [4 hh][8 r][64 e] f32 = 8,192 B overlay

    int tid = threadIdx.x;
    int w = tid >> 6;
    int lane = tid & 63;
    int quad = lane >> 4;
    int l15 = lane & 15;
    int hh = w & 3;
    int half = w >> 2;
    int b = blockIdx.x >> 7;
    int i0 = (blockIdx.x & 127) * 8;
    int bh = b * Hn + hh;
    int J0 = half * 512;

    const int* adj_base = adj + ((size_t)(b * Nn + i0)) * Nn + J0;
    const float* edst = e_dst + (size_t)bh * Tn * Nn + J0;
    const unsigned short* hTb = hT + (size_t)bh * HOn * Nn;

    f32x4 acc[4] = {{0.f, 0.f, 0.f, 0.f}, {0.f, 0.f, 0.f, 0.f},
                    {0.f, 0.f, 0.f, 0.f}, {0.f, 0.f, 0.f, 0.f}};
    float pl[8];
#pragma unroll
    for (int r = 0; r < 8; r++) pl[r] = 0.f;

    // zero A-frag rows 8-15 of own wave's P region (544 u32)
    {
        unsigned* pz = (unsigned*)&p_lds[w][8][0];
#pragma unroll
        for (int z = lane; z < 544; z += 64) pz[z] = 0;
    }

    // prefetch adj rows 0-3 of chunk 0 + ed chunk 0 (regs)
    int2 bufA[4], bufB[4];
#pragma unroll
    for (int r = 0; r < 4; r++) bufA[r] = *(const int2*)(adj_base + (size_t)r * Nn + 2 * lane);
    float2 edc[Tn], edn[Tn];
#pragma unroll
    for (int t = 0; t < Tn; t++) edc[t] = *(const float2*)(edst + t * Nn + 2 * lane);

    // es table (per head, 5 t x 8 rows)
    if (w < 4 && lane < 40) {
        const float* esrc = e_src + (size_t)bh * Tn * Nn;
        es_lds[w][lane >> 3][lane & 7] = esrc[(lane >> 3) * Nn + i0 + (lane & 7)];
    }
    __syncthreads();

// pass-1 body: p = exp(leakyrelu(es+ed)), masked -> 0; register cndmask selects
#define P1ROW(ROW, AV)                                                          \
    {                                                                           \
        int aa[2] = {(AV).x, (AV).y};                                           \
        float es0 = es_lds[hh][0][ROW], es1 = es_lds[hh][1][ROW];               \
        float es2 = es_lds[hh][2][ROW], es3 = es_lds[hh][3][ROW];               \
        float es4 = es_lds[hh][4][ROW];                                         \
        float p01[2];                                                           \
        _Pragma("unroll")                                                       \
        for (int s = 0; s < 2; s++) {                                           \
            int a = aa[s];                                                      \
            bool c2 = (a == 2), c3 = (a == 3), c4 = (a == 4), c5 = (a == 5);    \
            float es = es0, ed = (s == 0) ? edc[0].x : edc[0].y;                \
            es = c2 ? es1 : es; ed = c2 ? ((s == 0) ? edc[1].x : edc[1].y) : ed;\
            es = c3 ? es2 : es; ed = c3 ? ((s == 0) ? edc[2].x : edc[2].y) : ed;\
            es = c4 ? es3 : es; ed = c4 ? ((s == 0) ? edc[3].x : edc[3].y) : ed;\
            es = c5 ? es4 : es; ed = c5 ? ((s == 0) ? edc[4].x : edc[4].y) : ed;\
            float x = es + ed;                                                  \
            x = fmaxf(x, 0.01f * x);                                            \
            float p = __expf(x);                                                \
            p = (a == 0) ? 0.f : p;                                             \
            pl[ROW] += p;                                                       \
            p01[s] = p;                                                         \
        }                                                                       \
        __hip_bfloat162 pp = __float22bfloat162_rn(make_float2(p01[0], p01[1]));\
        unsigned pu; __builtin_memcpy(&pu, &pp, 4);                             \
        *(unsigned*)(&p_lds[w][ROW][2 * lane]) = pu;                            \
    }

#pragma unroll 1
    for (int c = 0; c < 4; c++) {
        int jc = c * 128;  // relative to J0
        // issue rows 4-7 of this chunk (consumed after rows 0-3's pass-1)
#pragma unroll
        for (int r = 0; r < 4; r++)
            bufB[r] = *(const int2*)(adj_base + (size_t)(4 + r) * Nn + jc + 2 * lane);
        // prefetch next chunk's ed into regs
        if (c < 3) {
#pragma unroll
            for (int t = 0; t < Tn; t++)
                edn[t] = *(const float2*)(edst + t * Nn + jc + 128 + 2 * lane);
        }
        // pass-1 rows 0-3 (bufA arrived during previous chunk / prologue)
#pragma unroll
        for (int r = 0; r < 4; r++) P1ROW(r, bufA[r]);
        // issue rows 0-3 of next chunk (covered by rows 4-7 pass + MFMA)
        if (c < 3) {
#pragma unroll
            for (int r = 0; r < 4; r++)
                bufA[r] = *(const int2*)(adj_base + (size_t)r * Nn + jc + 128 + 2 * lane);
        }
        // pass-1 rows 4-7
#pragma unroll
        for (int r = 0; r < 4; r++) P1ROW(4 + r, bufB[r]);
        if (c < 3) {
#pragma unroll
            for (int t = 0; t < Tn; t++) edc[t] = edn[t];
        }
        // PV via MFMA: A = P (own-wave LDS, b128 reads), B = hT (L2-hot)
#pragma unroll
        for (int k = 0; k < 4; k++) {
            bf16x8 Afr = *(const bf16x8*)(&p_lds[w][l15][k * 32 + quad * 8]);
#pragma unroll
            for (int et = 0; et < 4; et++) {
                bf16x8 Bf = *(const bf16x8*)(hTb + (size_t)(et * 16 + l15) * Nn + J0 + jc + k * 32 + quad * 8);
                acc[et] = __builtin_amdgcn_mfma_f32_16x16x32_bf16(Afr, Bf, acc[et], 0, 0, 0);
            }
        }
    }
#undef P1ROW

    // per-wave l reduction: butterfly over 64 lanes
#pragma unroll
    for (int r = 0; r < 8; r++) {
#pragma unroll
        for (int off = 1; off < 64; off <<= 1) pl[r] += __shfl_xor(pl[r], off);
    }
    if (lane == 0) {
#pragma unroll
        for (int r = 0; r < 8; r++) l_lds[w][r] = pl[r];
    }
    __syncthreads();  // all waves done with p_lds (MFMA reads) before macc overlay
    if (w >= 4) {
        if (quad < 2) {  // only rows 0-7 valid (r = quad*4+reg)
#pragma unroll
            for (int et = 0; et < 4; et++)
#pragma unroll
                for (int reg = 0; reg < 4; reg++)
                    macc[((hh * 8) + quad * 4 + reg) * 64 + et * 16 + l15] = acc[et][reg];
        }
        __syncthreads();
        return;
    }
    __syncthreads();

    // merge + epilogue (rows 0-7 -> quads 0,1): /l, +bias, relu, +h, LayerNorm, store f32
    if (quad < 2) {
        float bv[4], gv[4], bev[4];
#pragma unroll
        for (int et = 0; et < 4; et++) {
            int e = et * 16 + l15;
            bv[et] = bias[hh * HOn + e];
            gv[et] = gamma[hh * HOn + e];
            bev[et] = beta[hh * HOn + e];
        }
#pragma unroll
        for (int reg = 0; reg < 4; reg++) {
            int r = quad * 4 + reg;
            int i = i0 + r;
            float lw = l_lds[w][r] + l_lds[w + 4][r];
            float linv = 1.f / fmaxf(lw, 1e-30f);
            float dv[4];
            float s = 0.f, ss = 0.f;
#pragma unroll
            for (int et = 0; et < 4; et++) {
                int e = et * 16 + l15;
                float v = (acc[et][reg] + macc[((hh * 8) + r) * 64 + e]) * linv + bv[et];
                v = (v > 0.f) ? v : 0.f;
                v += b2f(hTb[(size_t)e * Nn + i]);  // residual h
                dv[et] = v;
                s += v;
                ss += v * v;
            }
#pragma unroll
            for (int off = 8; off; off >>= 1) {
                s += __shfl_xor(s, off);
                ss += __shfl_xor(ss, off);
            }
            float mean = s * (1.f / 64.f);
            float var = ss * (1.f / 64.f) - mean * mean;
            float rstd = rsqrtf(var + 1e-6f);
#pragma unroll
            for (int et = 0; et < 4; et++) {
                int e = et * 16 + l15;
                float o = (dv[et] - mean) * rstd * gv[et] + bev[et];
                out[((size_t)(b * Nn + i)) * (Hn * HOn) + hh * HOn + e] = o;
            }
        }
    }
}

extern "C" void kernel_launch(void* const* d_in, const int* in_sizes, int n_in,
                              void* d_out, int out_size, void* d_ws, size_t ws_size,
                              hipStream_t stream) {
    const float* X = (const float*)d_in[0];        // nodes_embed f32 [B,N,D]
    const int* adj = (const int*)d_in[1];          // node_adj int32 [B,N,N]
    const float* W = (const float*)d_in[2];        // [H,D,HO] f32
    const float* a_src = (const float*)d_in[3];    // [H,T,HO] f32
    const float* a_dst = (const float*)d_in[4];    // [H,T,HO] f32
    const float* bias = (const float*)d_in[5];     // [H,HO] f32
    const float* gamma = (const float*)d_in[6];    // [H,HO] f32
    const float* beta = (const float*)d_in[7];     // [H,HO] f32
    float* out = (float*)d_out;                    // [B,N,H*HO] f32

    char* ws = (char*)d_ws;
    size_t off = 0;
    unsigned short* hT = (unsigned short*)(ws + off);  off += (size_t)Bn * Hn * Nn * HOn * 2;  // 4 MB
    unsigned short* WT = (unsigned short*)(ws + off);  off += (size_t)Hn * WTR * Dn * 2;       // 160 KB
    float* e_src = (float*)(ws + off);                 off += (size_t)Bn * Hn * Tn * Nn * 4;   // 640 KB
    float* e_dst = (float*)(ws + off);                 off += (size_t)Bn * Hn * Tn * Nn * 4;   // 640 KB

    if (ws_size < off) {
        k_signal<<<(out_size + 255) / 256, 256, 0, stream>>>(out, out_size);
        return;
    }

    k_transpose_w<<<Hn * (Dn / 64), 256, 0, stream>>>(W, a_src, a_dst, WT);
    k_proj<<<Bn * (Nn / 16), 256, 0, stream>>>(X, WT, hT, e_src, e_dst);
    k_attn<<<Bn * (Nn / 8), 512, 0, stream>>>(adj, e_src, e_dst, hT, bias, gamma, beta, out);
}

// Round 12
// 156.076 us; speedup vs baseline: 1.2227x; 1.2227x over previous
//
#include <hip/hip_runtime.h>
#include <hip/hip_bf16.h>

#define Bn 8
#define Nn 1024
#define Dn 256
#define Hn 4
#define HOn 64
#define Tn 5
#define WTR 80   // WT rows per head: 64 W^T cols + 10 Wa rows + 6 zero pad

typedef short bf16x8 __attribute__((ext_vector_type(8)));
typedef float f32x4 __attribute__((ext_vector_type(4)));

__device__ __forceinline__ float b2f(unsigned short u) {
    unsigned x = ((unsigned)u) << 16;
    float f;
    __builtin_memcpy(&f, &x, 4);
    return f;
}
// fast RNE f32->bf16 (finite inputs only)
__device__ __forceinline__ unsigned bfr(float f) {
    unsigned u;
    __builtin_memcpy(&u, &f, 4);
    return (u + 0x7FFFu + ((u >> 16) & 1u)) >> 16;
}
__device__ __forceinline__ unsigned short f2b(float f) { return (unsigned short)bfr(f); }

// ---------- fallback: signal "workspace too small" with out = 100.0 ----------
__global__ __launch_bounds__(256) void k_signal(float* __restrict__ out, int n) {
    int i = blockIdx.x * 256 + threadIdx.x;
    if (i < n) out[i] = 100.0f;
}

// ---------- kernel 0: WT [H][80][D] bf16: rows 0-63 = W^T, 64-73 = W.a_src|W.a_dst, 74-79 = 0
__global__ __launch_bounds__(256) void k_transpose_w(const float* __restrict__ W,
                                                     const float* __restrict__ a_src,
                                                     const float* __restrict__ a_dst,
                                                     unsigned short* __restrict__ WT) {
    __shared__ float tile[64][65];
    int h = blockIdx.x >> 2;
    int d0 = (blockIdx.x & 3) * 64;
    int c0 = threadIdx.x & 63;
    int r0 = threadIdx.x >> 6;  // 0..3
#pragma unroll
    for (int r = 0; r < 16; r++) {
        int d = r * 4 + r0;
        tile[d][c0] = W[((size_t)(h * Dn + d0 + d)) * HOn + c0];  // coalesced over e
    }
    __syncthreads();
#pragma unroll
    for (int r = 0; r < 16; r++) {
        int e = r * 4 + r0;
        WT[((size_t)(h * WTR + e)) * Dn + d0 + c0] = f2b(tile[c0][e]);
    }
    for (int t = r0; t < 2 * Tn; t += 4) {
        const float* av = (t < Tn) ? (a_src + (h * Tn + t) * HOn)
                                   : (a_dst + (h * Tn + t - Tn) * HOn);
        float s = 0.f;
#pragma unroll
        for (int e = 0; e < HOn; e++) s += tile[c0][e] * av[e];
        WT[((size_t)(h * WTR + 64 + t)) * Dn + d0 + c0] = f2b(s);
    }
    for (int rr = 74 + r0; rr < WTR; rr += 4)
        WT[((size_t)(h * WTR + rr)) * Dn + d0 + c0] = 0;
}

// ---------- kernel 1: h^T = W^T x X^T via MFMA (A = W^T so C/D col = i -> coalesced stores)
// grid: B * (N/16) blocks x 256 threads; wave w = head w.
__global__ __launch_bounds__(256) void k_proj(const float* __restrict__ X,
                                              const unsigned short* __restrict__ WT,
                                              unsigned short* __restrict__ hT,
                                              float* __restrict__ e_src,
                                              float* __restrict__ e_dst) {
    int tid = threadIdx.x;
    int w = tid >> 6;
    int lane = tid & 63;
    int quad = lane >> 4;
    int l15 = lane & 15;
    int b = blockIdx.x >> 6;
    int i0 = (blockIdx.x & 63) * 16;
    int h = w;
    int bh = b * Hn + h;

    // B-frag: B[k=quad*8+idx (=d)][n=l15 (=i)] <- X rows, f32 -> bf16 via cvt_pk
    bf16x8 Bx[8];
    const float* xf = X + ((size_t)(b * Nn + i0 + l15)) * Dn + quad * 8;
#pragma unroll
    for (int kc = 0; kc < 8; kc++) {
        union { bf16x8 v; unsigned u[4]; } uu;
        const float4* xp = (const float4*)(xf + kc * 32);
        float4 A0 = xp[0], A1 = xp[1];
        __hip_bfloat162 h0 = __float22bfloat162_rn(make_float2(A0.x, A0.y));
        __hip_bfloat162 h1 = __float22bfloat162_rn(make_float2(A0.z, A0.w));
        __hip_bfloat162 h2 = __float22bfloat162_rn(make_float2(A1.x, A1.y));
        __hip_bfloat162 h3 = __float22bfloat162_rn(make_float2(A1.z, A1.w));
        __builtin_memcpy(&uu.u[0], &h0, 4);
        __builtin_memcpy(&uu.u[1], &h1, 4);
        __builtin_memcpy(&uu.u[2], &h2, 4);
        __builtin_memcpy(&uu.u[3], &h3, 4);
        Bx[kc] = uu.v;
    }

    f32x4 acc[5] = {{0.f, 0.f, 0.f, 0.f}, {0.f, 0.f, 0.f, 0.f}, {0.f, 0.f, 0.f, 0.f},
                    {0.f, 0.f, 0.f, 0.f}, {0.f, 0.f, 0.f, 0.f}};
    const unsigned short* wbase = WT + (size_t)h * WTR * Dn;
#pragma unroll
    for (int kc = 0; kc < 8; kc++) {
#pragma unroll
        for (int et = 0; et < 5; et++) {
            // A-frag: A[m=l15 (=e-in-16)][k=quad*8+idx (=d)] <- WT rows
            bf16x8 Aw = *(const bf16x8*)(wbase + (size_t)(et * 16 + l15) * Dn + kc * 32 + quad * 8);
            acc[et] = __builtin_amdgcn_mfma_f32_16x16x32_bf16(Aw, Bx[kc], acc[et], 0, 0, 0);
        }
    }

    // C/D: col=l15 -> i, row=quad*4+reg -> m. hT stores: 16 lanes x 2B contiguous per (et,quad,reg)
#pragma unroll
    for (int et = 0; et < 4; et++) {
#pragma unroll
        for (int reg = 0; reg < 4; reg++) {
            int e = et * 16 + quad * 4 + reg;
            hT[((size_t)bh * HOn + e) * Nn + i0 + l15] = f2b(acc[et][reg]);
        }
    }
    // 5th tile rows: t = quad*4+reg (0-4: e_src, 5-9: e_dst, 10-15: pad)
#pragma unroll
    for (int reg = 0; reg < 4; reg++) {
        int t = quad * 4 + reg;
        if (t < Tn)
            e_src[((size_t)bh * Tn + t) * Nn + i0 + l15] = acc[4][reg];
        else if (t < 2 * Tn)
            e_dst[((size_t)bh * Tn + (t - Tn)) * Nn + i0 + l15] = acc[4][reg];
    }
}

// ---------- kernel 2: fused attention; hybrid pass-1 (es cndmask + ed LDS), staged B-frags ----------
// grid: B * (N/16) = 512 blocks x 512 threads (8 waves); wave = (head = w&3, j-half = w>>2).
// NOTE: no min-waves (R7 spill); chunk loop rolled (R8 spill); 16-row tiles (R11: VGPR>64 caps
// residency at 4 waves/SIMD, more blocks only doubles overhead); es via cndmask not LDS gather
// (R10: data-dependent est reads = 13-way conflicts, 6.1M cycles).
__global__ __launch_bounds__(512) void k_attn(const int* __restrict__ adj,
                                              const float* __restrict__ e_src,
                                              const float* __restrict__ e_dst,
                                              const unsigned short* __restrict__ hT,
                                              const float* __restrict__ bias,
                                              const float* __restrict__ gamma,
                                              const float* __restrict__ beta,
                                              float* __restrict__ out) {
    // p_lds row stride 136 u16 = 272 B (16B-aligned -> ds_read_b128 A-frags).
    // After the chunk loop waves 4-7's p regions are dead; macc (16 KB) overlays p_lds[4..7].
    __shared__ __align__(16) unsigned short p_lds[8][16][136];  // 34,816 B
    __shared__ float edt[8][5][132];                            // per-wave ed table, 21,120 B
    __shared__ float es_lds[4][5][16];                          // per-head es values, 1,280 B
    __shared__ float l_lds[8][16];                              // 512 B
    float* macc = (float*)&p_lds[4][0][0];  // [4 hh][16 r][64 e] f32 overlay (16,384 <= 17,408 B)

    int tid = threadIdx.x;
    int w = tid >> 6;
    int lane = tid & 63;
    int quad = lane >> 4;
    int l15 = lane & 15;
    int hh = w & 3;
    int half = w >> 2;
    int b = blockIdx.x >> 6;
    int i0 = (blockIdx.x & 63) * 16;
    int bh = b * Hn + hh;
    int J0 = half * 512;

    const int* adj_base = adj + ((size_t)(b * Nn + i0)) * Nn + J0;
    const float* edst = e_dst + (size_t)bh * Tn * Nn + J0;
    const unsigned short* hTb = hT + (size_t)bh * HOn * Nn;

    f32x4 acc[4] = {{0.f, 0.f, 0.f, 0.f}, {0.f, 0.f, 0.f, 0.f},
                    {0.f, 0.f, 0.f, 0.f}, {0.f, 0.f, 0.f, 0.f}};
    float pl[16];
#pragma unroll
    for (int r = 0; r < 16; r++) pl[r] = 0.f;

    // prefetch adj rows 0-7 of chunk 0 + ed chunk 0 (regs)
    int2 bufA[8], bufB[8];
#pragma unroll
    for (int r = 0; r < 8; r++) bufA[r] = *(const int2*)(adj_base + (size_t)r * Nn + 2 * lane);
    float2 edc[Tn];
#pragma unroll
    for (int t = 0; t < Tn; t++) edc[t] = *(const float2*)(edst + t * Nn + 2 * lane);

    // es values (per head, 5 t x 16 rows)
    if (w < 4) {
        const float* esrc = e_src + (size_t)bh * Tn * Nn;
#pragma unroll
        for (int idx = lane; idx < 80; idx += 64) {
            int t = idx >> 4, row = idx & 15;
            es_lds[w][t][row] = esrc[t * Nn + i0 + row];
        }
    }
    __syncthreads();

// pass-1: p = exp(leakyrelu(es_sel + ed_lds)), masked -> 0.
// es: broadcast reads + cndmask (conflict-free); ed: edt LDS lookup (~4-way, cheap).
#define P1ROW(ROW, AV)                                                          \
    {                                                                           \
        int a0 = (AV).x, a1 = (AV).y;                                           \
        int t0 = a0 - 1; t0 = (t0 < 0) ? 0 : t0;                                \
        int t1 = a1 - 1; t1 = (t1 < 0) ? 0 : t1;                                \
        float ed0 = edt[w][t0][2 * lane];                                       \
        float ed1 = edt[w][t1][2 * lane + 1];                                   \
        float es0 = es_lds[hh][0][ROW], es1 = es_lds[hh][1][ROW];               \
        float es2 = es_lds[hh][2][ROW], es3 = es_lds[hh][3][ROW];               \
        float es4 = es_lds[hh][4][ROW];                                         \
        float e0 = es0, e1 = es0;                                               \
        e0 = (t0 == 1) ? es1 : e0; e1 = (t1 == 1) ? es1 : e1;                   \
        e0 = (t0 == 2) ? es2 : e0; e1 = (t1 == 2) ? es2 : e1;                   \
        e0 = (t0 == 3) ? es3 : e0; e1 = (t1 == 3) ? es3 : e1;                   \
        e0 = (t0 == 4) ? es4 : e0; e1 = (t1 == 4) ? es4 : e1;                   \
        float x0 = e0 + ed0; x0 = fmaxf(x0, 0.01f * x0);                        \
        float x1 = e1 + ed1; x1 = fmaxf(x1, 0.01f * x1);                        \
        float p0 = __expf(x0); p0 = (a0 == 0) ? 0.f : p0;                       \
        float p1 = __expf(x1); p1 = (a1 == 0) ? 0.f : p1;                       \
        pl[ROW] += p0 + p1;                                                     \
        __hip_bfloat162 pp = __float22bfloat162_rn(make_float2(p0, p1));        \
        unsigned pu; __builtin_memcpy(&pu, &pp, 4);                             \
        *(unsigned*)(&p_lds[w][ROW][2 * lane]) = pu;                            \
    }

#pragma unroll 1
    for (int c = 0; c < 4; c++) {
        int jc = c * 128;  // relative to J0
        // publish this chunk's ed table from edc (wave-internal lgkm ordering suffices)
#pragma unroll
        for (int t = 0; t < Tn; t++) *(float2*)(&edt[w][t][2 * lane]) = edc[t];
        // issue rows 8-15 of this chunk's adj
#pragma unroll
        for (int r = 0; r < 8; r++)
            bufB[r] = *(const int2*)(adj_base + (size_t)(8 + r) * Nn + jc + 2 * lane);
        // edc regs now dead -> start next chunk's ed loads (L2-hot)
        if (c < 3) {
#pragma unroll
            for (int t = 0; t < Tn; t++)
                edc[t] = *(const float2*)(edst + t * Nn + jc + 128 + 2 * lane);
        }
        // B-frag k=0 prefetch (consumed after pass-1 -> full latency cover)
        bf16x8 Bfp[4];
#pragma unroll
        for (int et = 0; et < 4; et++)
            Bfp[et] = *(const bf16x8*)(hTb + (size_t)(et * 16 + l15) * Nn + J0 + jc + quad * 8);
        // pass-1 rows 0-7 (bufA arrived during previous chunk / prologue)
#pragma unroll
        for (int r = 0; r < 8; r++) P1ROW(r, bufA[r]);
        // issue rows 0-7 of next chunk's adj
        if (c < 3) {
#pragma unroll
            for (int r = 0; r < 8; r++)
                bufA[r] = *(const int2*)(adj_base + (size_t)r * Nn + jc + 128 + 2 * lane);
        }
        // pass-1 rows 8-15
#pragma unroll
        for (int r = 0; r < 8; r++) P1ROW(8 + r, bufB[r]);
        // PV via MFMA: A = P (own-wave LDS, b128), B staged one batch ahead
        bf16x8 Bf1[4], Bf2[4], Bf3[4];
#pragma unroll
        for (int et = 0; et < 4; et++)
            Bf1[et] = *(const bf16x8*)(hTb + (size_t)(et * 16 + l15) * Nn + J0 + jc + 32 + quad * 8);
        {
            bf16x8 Afr = *(const bf16x8*)(&p_lds[w][l15][quad * 8]);
#pragma unroll
            for (int et = 0; et < 4; et++)
                acc[et] = __builtin_amdgcn_mfma_f32_16x16x32_bf16(Afr, Bfp[et], acc[et], 0, 0, 0);
        }
#pragma unroll
        for (int et = 0; et < 4; et++)
            Bf2[et] = *(const bf16x8*)(hTb + (size_t)(et * 16 + l15) * Nn + J0 + jc + 64 + quad * 8);
        {
            bf16x8 Afr = *(const bf16x8*)(&p_lds[w][l15][32 + quad * 8]);
#pragma unroll
            for (int et = 0; et < 4; et++)
                acc[et] = __builtin_amdgcn_mfma_f32_16x16x32_bf16(Afr, Bf1[et], acc[et], 0, 0, 0);
        }
#pragma unroll
        for (int et = 0; et < 4; et++)
            Bf3[et] = *(const bf16x8*)(hTb + (size_t)(et * 16 + l15) * Nn + J0 + jc + 96 + quad * 8);
        {
            bf16x8 Afr = *(const bf16x8*)(&p_lds[w][l15][64 + quad * 8]);
#pragma unroll
            for (int et = 0; et < 4; et++)
                acc[et] = __builtin_amdgcn_mfma_f32_16x16x32_bf16(Afr, Bf2[et], acc[et], 0, 0, 0);
        }
        {
            bf16x8 Afr = *(const bf16x8*)(&p_lds[w][l15][96 + quad * 8]);
#pragma unroll
            for (int et = 0; et < 4; et++)
                acc[et] = __builtin_amdgcn_mfma_f32_16x16x32_bf16(Afr, Bf3[et], acc[et], 0, 0, 0);
        }
    }
#undef P1ROW

    // per-wave l reduction: butterfly over 64 lanes
#pragma unroll
    for (int r = 0; r < 16; r++) {
#pragma unroll
        for (int off = 1; off < 64; off <<= 1) pl[r] += __shfl_xor(pl[r], off);
    }
    if (lane == 0) {
#pragma unroll
        for (int r = 0; r < 16; r++) l_lds[w][r] = pl[r];
    }
    __syncthreads();  // all waves done with p_lds (MFMA reads) before macc overlay
    if (w >= 4) {
#pragma unroll
        for (int et = 0; et < 4; et++)
#pragma unroll
            for (int reg = 0; reg < 4; reg++)
                macc[((hh * 16) + quad * 4 + reg) * 64 + et * 16 + l15] = acc[et][reg];
    }
    __syncthreads();
    if (w >= 4) return;

    // merge + epilogue: /l, +bias, relu, +h, LayerNorm over HO, store f32
    float bv[4], gv[4], bev[4];
#pragma unroll
    for (int et = 0; et < 4; et++) {
        int e = et * 16 + l15;
        bv[et] = bias[hh * HOn + e];
        gv[et] = gamma[hh * HOn + e];
        bev[et] = beta[hh * HOn + e];
    }
#pragma unroll
    for (int reg = 0; reg < 4; reg++) {
        int r = quad * 4 + reg;
        int i = i0 + r;
        float lw = l_lds[w][r] + l_lds[w + 4][r];
        float linv = 1.f / fmaxf(lw, 1e-30f);
        float dv[4];
        float s = 0.f, ss = 0.f;
#pragma unroll
        for (int et = 0; et < 4; et++) {
            int e = et * 16 + l15;
            float v = (acc[et][reg] + macc[((hh * 16) + r) * 64 + e]) * linv + bv[et];
            v = (v > 0.f) ? v : 0.f;
            v += b2f(hTb[(size_t)e * Nn + i]);  // residual h
            dv[et] = v;
            s += v;
            ss += v * v;
        }
#pragma unroll
        for (int off = 8; off; off >>= 1) {
            s += __shfl_xor(s, off);
            ss += __shfl_xor(ss, off);
        }
        float mean = s * (1.f / 64.f);
        float var = ss * (1.f / 64.f) - mean * mean;
        float rstd = rsqrtf(var + 1e-6f);
#pragma unroll
        for (int et = 0; et < 4; et++) {
            int e = et * 16 + l15;
            float o = (dv[et] - mean) * rstd * gv[et] + bev[et];
            out[((size_t)(b * Nn + i)) * (Hn * HOn) + hh * HOn + e] = o;
        }
    }
}

extern "C" void kernel_launch(void* const* d_in, const int* in_sizes, int n_in,
                              void* d_out, int out_size, void* d_ws, size_t ws_size,
                              hipStream_t stream) {
    const float* X = (const float*)d_in[0];        // nodes_embed f32 [B,N,D]
    const int* adj = (const int*)d_in[1];          // node_adj int32 [B,N,N]
    const float* W = (const float*)d_in[2];        // [H,D,HO] f32
    const float* a_src = (const float*)d_in[3];    // [H,T,HO] f32
    const float* a_dst = (const float*)d_in[4];    // [H,T,HO] f32
    const float* bias = (const float*)d_in[5];     // [H,HO] f32
    const float* gamma = (const float*)d_in[6];    // [H,HO] f32
    const float* beta = (const float*)d_in[7];     // [H,HO] f32
    float* out = (float*)d_out;                    // [B,N,H*HO] f32

    char* ws = (char*)d_ws;
    size_t off = 0;
    unsigned short* hT = (unsigned short*)(ws + off);  off += (size_t)Bn * Hn * Nn * HOn * 2;  // 4 MB
    unsigned short* WT = (unsigned short*)(ws + off);  off += (size_t)Hn * WTR * Dn * 2;       // 160 KB
    float* e_src = (float*)(ws + off);                 off += (size_t)Bn * Hn * Tn * Nn * 4;   // 640 KB
    float* e_dst = (float*)(ws + off);                 off += (size_t)Bn * Hn * Tn * Nn * 4;   // 640 KB

    if (ws_size < off) {
        k_signal<<<(out_size + 255) / 256, 256, 0, stream>>>(out, out_size);
        return;
    }

    k_transpose_w<<<Hn * (Dn / 64), 256, 0, stream>>>(W, a_src, a_dst, WT);
    k_proj<<<Bn * (Nn / 16), 256, 0, stream>>>(X, WT, hT, e_src, e_dst);
    k_attn<<<Bn * (Nn / 16), 512, 0, stream>>>(adj, e_src, e_dst, hT, bias, gamma, beta, out);
}

// Round 13
// 151.314 us; speedup vs baseline: 1.2612x; 1.0315x over previous
//
#include <hip/hip_runtime.h>
#include <hip/hip_bf16.h>

#define Bn 8
#define Nn 1024
#define Dn 256
#define Hn 4
#define HOn 64
#define Tn 5
#define WTR 80   // WT rows per head: 64 W^T cols + 10 Wa rows + 6 zero pad

typedef short bf16x8 __attribute__((ext_vector_type(8)));
typedef float f32x4 __attribute__((ext_vector_type(4)));

__device__ __forceinline__ float b2f(unsigned short u) {
    unsigned x = ((unsigned)u) << 16;
    float f;
    __builtin_memcpy(&f, &x, 4);
    return f;
}
// fast RNE f32->bf16 (finite inputs only)
__device__ __forceinline__ unsigned bfr(float f) {
    unsigned u;
    __builtin_memcpy(&u, &f, 4);
    return (u + 0x7FFFu + ((u >> 16) & 1u)) >> 16;
}
__device__ __forceinline__ unsigned short f2b(float f) { return (unsigned short)bfr(f); }

// ---------- fallback: signal "workspace too small" with out = 100.0 ----------
__global__ __launch_bounds__(256) void k_signal(float* __restrict__ out, int n) {
    int i = blockIdx.x * 256 + threadIdx.x;
    if (i < n) out[i] = 100.0f;
}

// ---------- kernel 0: WT [H][80][D] bf16: rows 0-63 = W^T, 64-73 = W.a_src|W.a_dst, 74-79 = 0
__global__ __launch_bounds__(256) void k_transpose_w(const float* __restrict__ W,
                                                     const float* __restrict__ a_src,
                                                     const float* __restrict__ a_dst,
                                                     unsigned short* __restrict__ WT) {
    __shared__ float tile[64][65];
    int h = blockIdx.x >> 2;
    int d0 = (blockIdx.x & 3) * 64;
    int c0 = threadIdx.x & 63;
    int r0 = threadIdx.x >> 6;  // 0..3
#pragma unroll
    for (int r = 0; r < 16; r++) {
        int d = r * 4 + r0;
        tile[d][c0] = W[((size_t)(h * Dn + d0 + d)) * HOn + c0];  // coalesced over e
    }
    __syncthreads();
#pragma unroll
    for (int r = 0; r < 16; r++) {
        int e = r * 4 + r0;
        WT[((size_t)(h * WTR + e)) * Dn + d0 + c0] = f2b(tile[c0][e]);
    }
    for (int t = r0; t < 2 * Tn; t += 4) {
        const float* av = (t < Tn) ? (a_src + (h * Tn + t) * HOn)
                                   : (a_dst + (h * Tn + t - Tn) * HOn);
        float s = 0.f;
#pragma unroll
        for (int e = 0; e < HOn; e++) s += tile[c0][e] * av[e];
        WT[((size_t)(h * WTR + 64 + t)) * Dn + d0 + c0] = f2b(s);
    }
    for (int rr = 74 + r0; rr < WTR; rr += 4)
        WT[((size_t)(h * WTR + rr)) * Dn + d0 + c0] = 0;
}

// ---------- kernel 1: h^T = W^T x X^T via MFMA (A = W^T so C/D col = i -> coalesced stores)
// grid: B * (N/16) blocks x 256 threads; wave w = head w.
__global__ __launch_bounds__(256) void k_proj(const float* __restrict__ X,
                                              const unsigned short* __restrict__ WT,
                                              unsigned short* __restrict__ hT,
                                              float* __restrict__ e_src,
                                              float* __restrict__ e_dst) {
    int tid = threadIdx.x;
    int w = tid >> 6;
    int lane = tid & 63;
    int quad = lane >> 4;
    int l15 = lane & 15;
    int b = blockIdx.x >> 6;
    int i0 = (blockIdx.x & 63) * 16;
    int h = w;
    int bh = b * Hn + h;

    // B-frag: B[k=quad*8+idx (=d)][n=l15 (=i)] <- X rows, f32 -> bf16 via cvt_pk
    bf16x8 Bx[8];
    const float* xf = X + ((size_t)(b * Nn + i0 + l15)) * Dn + quad * 8;
#pragma unroll
    for (int kc = 0; kc < 8; kc++) {
        union { bf16x8 v; unsigned u[4]; } uu;
        const float4* xp = (const float4*)(xf + kc * 32);
        float4 A0 = xp[0], A1 = xp[1];
        __hip_bfloat162 h0 = __float22bfloat162_rn(make_float2(A0.x, A0.y));
        __hip_bfloat162 h1 = __float22bfloat162_rn(make_float2(A0.z, A0.w));
        __hip_bfloat162 h2 = __float22bfloat162_rn(make_float2(A1.x, A1.y));
        __hip_bfloat162 h3 = __float22bfloat162_rn(make_float2(A1.z, A1.w));
        __builtin_memcpy(&uu.u[0], &h0, 4);
        __builtin_memcpy(&uu.u[1], &h1, 4);
        __builtin_memcpy(&uu.u[2], &h2, 4);
        __builtin_memcpy(&uu.u[3], &h3, 4);
        Bx[kc] = uu.v;
    }

    f32x4 acc[5] = {{0.f, 0.f, 0.f, 0.f}, {0.f, 0.f, 0.f, 0.f}, {0.f, 0.f, 0.f, 0.f},
                    {0.f, 0.f, 0.f, 0.f}, {0.f, 0.f, 0.f, 0.f}};
    const unsigned short* wbase = WT + (size_t)h * WTR * Dn;
#pragma unroll
    for (int kc = 0; kc < 8; kc++) {
#pragma unroll
        for (int et = 0; et < 5; et++) {
            // A-frag: A[m=l15 (=e-in-16)][k=quad*8+idx (=d)] <- WT rows
            bf16x8 Aw = *(const bf16x8*)(wbase + (size_t)(et * 16 + l15) * Dn + kc * 32 + quad * 8);
            acc[et] = __builtin_amdgcn_mfma_f32_16x16x32_bf16(Aw, Bx[kc], acc[et], 0, 0, 0);
        }
    }

    // C/D: col=l15 -> i, row=quad*4+reg -> m. hT stores: 16 lanes x 2B contiguous per (et,quad,reg)
#pragma unroll
    for (int et = 0; et < 4; et++) {
#pragma unroll
        for (int reg = 0; reg < 4; reg++) {
            int e = et * 16 + quad * 4 + reg;
            hT[((size_t)bh * HOn + e) * Nn + i0 + l15] = f2b(acc[et][reg]);
        }
    }
    // 5th tile rows: t = quad*4+reg (0-4: e_src, 5-9: e_dst, 10-15: pad)
#pragma unroll
    for (int reg = 0; reg < 4; reg++) {
        int t = quad * 4 + reg;
        if (t < Tn)
            e_src[((size_t)bh * Tn + t) * Nn + i0 + l15] = acc[4][reg];
        else if (t < 2 * Tn)
            e_dst[((size_t)bh * Tn + (t - Tn)) * Nn + i0 + l15] = acc[4][reg];
    }
}

// ---------- kernel 2: fused attention — VGPR/LDS diet for 3 blocks/CU ----------
// grid: B * (N/16) = 512 blocks x 512 threads (8 waves); wave = (head = w&3, j-half = w>>2).
// Occupancy is block-granular: need LDS <= 53.3 KB (now 37.4) AND VGPR <= 85 (6 waves/SIMD)
// for 3 blocks/CU = 24 waves. Diet: l computed via 5th MFMA tile (B = ones) instead of pl[16]
// regs + butterfly; es via conflict-free LDS broadcast [row][t] (5 distinct banks); ed via
// register cndmask (edt table dropped: -21 KB LDS; R12 showed its gather = 4M conflict cyc);
// 4-row rolling adj buffers. NOTE: no min-waves (R7 spill); chunk loop rolled (R8 spill).
__global__ __launch_bounds__(512) void k_attn(const int* __restrict__ adj,
                                              const float* __restrict__ e_src,
                                              const float* __restrict__ e_dst,
                                              const unsigned short* __restrict__ hT,
                                              const float* __restrict__ bias,
                                              const float* __restrict__ gamma,
                                              const float* __restrict__ beta,
                                              float* __restrict__ out) {
    // p_lds row stride 136 u16 = 272 B (16B-aligned -> ds_read_b128 A-frags).
    // After the chunk loop waves 4-7's p regions are dead; macc (16 KB) overlays p_lds[4..7].
    __shared__ __align__(16) unsigned short p_lds[8][16][136];  // 34,816 B
    __shared__ float es2[4][16][8];                             // [hh][row][t] broadcast, 2,048 B
    __shared__ float l_lds[8][16];                              // 512 B
    float* macc = (float*)&p_lds[4][0][0];  // [4 hh][16 r][64 e] f32 overlay (16,384 <= 17,408 B)

    int tid = threadIdx.x;
    int w = tid >> 6;
    int lane = tid & 63;
    int quad = lane >> 4;
    int l15 = lane & 15;
    int hh = w & 3;
    int half = w >> 2;
    int b = blockIdx.x >> 6;
    int i0 = (blockIdx.x & 63) * 16;
    int bh = b * Hn + hh;
    int J0 = half * 512;

    const int* adj_base = adj + ((size_t)(b * Nn + i0)) * Nn + J0;
    const float* edst = e_dst + (size_t)bh * Tn * Nn + J0;
    const unsigned short* hTb = hT + (size_t)bh * HOn * Nn;

    f32x4 acc[4] = {{0.f, 0.f, 0.f, 0.f}, {0.f, 0.f, 0.f, 0.f},
                    {0.f, 0.f, 0.f, 0.f}, {0.f, 0.f, 0.f, 0.f}};
    f32x4 accl = {0.f, 0.f, 0.f, 0.f};  // l row-sums via MFMA with B = ones
    // bf16 1.0 = 0x3F80
    bf16x8 ONES;
    {
        short o = (short)0x3F80;
        ONES = (bf16x8){o, o, o, o, o, o, o, o};
    }

    // prefetch adj rows 0-3 of chunk 0
    int2 bufA[4], bufB[4];
#pragma unroll
    for (int r = 0; r < 4; r++) bufA[r] = *(const int2*)(adj_base + (size_t)r * Nn + 2 * lane);

    // es2[hh][row][t] staging (waves 0-3; waves 4-7 share head data)
    if (w < 4) {
        const float* esrc = e_src + (size_t)bh * Tn * Nn;
#pragma unroll
        for (int idx = lane; idx < 80; idx += 64) {
            int t = idx >> 4, row = idx & 15;
            es2[w][row][t] = esrc[t * Nn + i0 + row];
        }
    }
    __syncthreads();

// pass-1: p = exp(leakyrelu(es2[row][t] + ed_sel)), masked -> 0.
// es: LDS broadcast (fixed row -> 5 distinct banks, conflict-free); ed: cndmask on edc regs.
#define P1ROW(ROW, AV)                                                          \
    {                                                                           \
        int a0 = (AV).x, a1 = (AV).y;                                           \
        int t0 = a0 - 1; t0 = (t0 < 0) ? 0 : t0;                                \
        int t1 = a1 - 1; t1 = (t1 < 0) ? 0 : t1;                                \
        float e0 = es2[hh][ROW][t0];                                            \
        float e1 = es2[hh][ROW][t1];                                            \
        float d0 = edc[0].x, d1 = edc[0].y;                                     \
        d0 = (t0 == 1) ? edc[1].x : d0; d1 = (t1 == 1) ? edc[1].y : d1;         \
        d0 = (t0 == 2) ? edc[2].x : d0; d1 = (t1 == 2) ? edc[2].y : d1;         \
        d0 = (t0 == 3) ? edc[3].x : d0; d1 = (t1 == 3) ? edc[3].y : d1;         \
        d0 = (t0 == 4) ? edc[4].x : d0; d1 = (t1 == 4) ? edc[4].y : d1;         \
        float x0 = e0 + d0; x0 = fmaxf(x0, 0.01f * x0);                         \
        float x1 = e1 + d1; x1 = fmaxf(x1, 0.01f * x1);                         \
        float p0 = __expf(x0); p0 = (a0 == 0) ? 0.f : p0;                       \
        float p1 = __expf(x1); p1 = (a1 == 0) ? 0.f : p1;                       \
        __hip_bfloat162 pp = __float22bfloat162_rn(make_float2(p0, p1));        \
        unsigned pu; __builtin_memcpy(&pu, &pp, 4);                             \
        *(unsigned*)(&p_lds[w][ROW][2 * lane]) = pu;                            \
    }

#pragma unroll 1
    for (int c = 0; c < 4; c++) {
        int jc = c * 128;  // relative to J0
        // ed for this chunk (L2-hot after first head touches it)
        float2 edc[Tn];
#pragma unroll
        for (int t = 0; t < Tn; t++) edc[t] = *(const float2*)(edst + t * Nn + jc + 2 * lane);
        // rolling 4-row adj buffers: A has rows 0-3 (from prev chunk / prologue)
#pragma unroll
        for (int r = 0; r < 4; r++)
            bufB[r] = *(const int2*)(adj_base + (size_t)(4 + r) * Nn + jc + 2 * lane);
#pragma unroll
        for (int r = 0; r < 4; r++) P1ROW(r, bufA[r]);
#pragma unroll
        for (int r = 0; r < 4; r++)
            bufA[r] = *(const int2*)(adj_base + (size_t)(8 + r) * Nn + jc + 2 * lane);
#pragma unroll
        for (int r = 0; r < 4; r++) P1ROW(4 + r, bufB[r]);
#pragma unroll
        for (int r = 0; r < 4; r++)
            bufB[r] = *(const int2*)(adj_base + (size_t)(12 + r) * Nn + jc + 2 * lane);
#pragma unroll
        for (int r = 0; r < 4; r++) P1ROW(8 + r, bufA[r]);
        if (c < 3) {
#pragma unroll
            for (int r = 0; r < 4; r++)
                bufA[r] = *(const int2*)(adj_base + (size_t)r * Nn + jc + 128 + 2 * lane);
        }
#pragma unroll
        for (int r = 0; r < 4; r++) P1ROW(12 + r, bufB[r]);
        // PV via MFMA: A = P (own-wave LDS, b128); 5th tile (B=ones) accumulates l row-sums
#pragma unroll
        for (int k = 0; k < 4; k++) {
            bf16x8 Afr = *(const bf16x8*)(&p_lds[w][l15][k * 32 + quad * 8]);
            accl = __builtin_amdgcn_mfma_f32_16x16x32_bf16(Afr, ONES, accl, 0, 0, 0);
#pragma unroll
            for (int et = 0; et < 4; et++) {
                bf16x8 Bf = *(const bf16x8*)(hTb + (size_t)(et * 16 + l15) * Nn + J0 + jc + k * 32 + quad * 8);
                acc[et] = __builtin_amdgcn_mfma_f32_16x16x32_bf16(Afr, Bf, acc[et], 0, 0, 0);
            }
        }
    }
#undef P1ROW

    // l: accl[reg] (any l15 col) = row-sum for row quad*4+reg
    if (l15 == 0) {
#pragma unroll
        for (int reg = 0; reg < 4; reg++) l_lds[w][quad * 4 + reg] = accl[reg];
    }
    __syncthreads();  // all waves done with p_lds (MFMA reads) before macc overlay
    if (w >= 4) {
#pragma unroll
        for (int et = 0; et < 4; et++)
#pragma unroll
            for (int reg = 0; reg < 4; reg++)
                macc[((hh * 16) + quad * 4 + reg) * 64 + et * 16 + l15] = acc[et][reg];
    }
    __syncthreads();
    if (w >= 4) return;

    // merge + epilogue: /l, +bias, relu, +h, LayerNorm over HO, store f32
    float bv[4], gv[4], bev[4];
#pragma unroll
    for (int et = 0; et < 4; et++) {
        int e = et * 16 + l15;
        bv[et] = bias[hh * HOn + e];
        gv[et] = gamma[hh * HOn + e];
        bev[et] = beta[hh * HOn + e];
    }
#pragma unroll
    for (int reg = 0; reg < 4; reg++) {
        int r = quad * 4 + reg;
        int i = i0 + r;
        float lw = l_lds[w][r] + l_lds[w + 4][r];
        float linv = 1.f / fmaxf(lw, 1e-30f);
        float dv[4];
        float s = 0.f, ss = 0.f;
#pragma unroll
        for (int et = 0; et < 4; et++) {
            int e = et * 16 + l15;
            float v = (acc[et][reg] + macc[((hh * 16) + r) * 64 + e]) * linv + bv[et];
            v = (v > 0.f) ? v : 0.f;
            v += b2f(hTb[(size_t)e * Nn + i]);  // residual h
            dv[et] = v;
            s += v;
            ss += v * v;
        }
#pragma unroll
        for (int off = 8; off; off >>= 1) {
            s += __shfl_xor(s, off);
            ss += __shfl_xor(ss, off);
        }
        float mean = s * (1.f / 64.f);
        float var = ss * (1.f / 64.f) - mean * mean;
        float rstd = rsqrtf(var + 1e-6f);
#pragma unroll
        for (int et = 0; et < 4; et++) {
            int e = et * 16 + l15;
            float o = (dv[et] - mean) * rstd * gv[et] + bev[et];
            out[((size_t)(b * Nn + i)) * (Hn * HOn) + hh * HOn + e] = o;
        }
    }
}

extern "C" void kernel_launch(void* const* d_in, const int* in_sizes, int n_in,
                              void* d_out, int out_size, void* d_ws, size_t ws_size,
                              hipStream_t stream) {
    const float* X = (const float*)d_in[0];        // nodes_embed f32 [B,N,D]
    const int* adj = (const int*)d_in[1];          // node_adj int32 [B,N,N]
    const float* W = (const float*)d_in[2];        // [H,D,HO] f32
    const float* a_src = (const float*)d_in[3];    // [H,T,HO] f32
    const float* a_dst = (const float*)d_in[4];    // [H,T,HO] f32
    const float* bias = (const float*)d_in[5];     // [H,HO] f32
    const float* gamma = (const float*)d_in[6];    // [H,HO] f32
    const float* beta = (const float*)d_in[7];     // [H,HO] f32
    float* out = (float*)d_out;                    // [B,N,H*HO] f32

    char* ws = (char*)d_ws;
    size_t off = 0;
    unsigned short* hT = (unsigned short*)(ws + off);  off += (size_t)Bn * Hn * Nn * HOn * 2;  // 4 MB
    unsigned short* WT = (unsigned short*)(ws + off);  off += (size_t)Hn * WTR * Dn * 2;       // 160 KB
    float* e_src = (float*)(ws + off);                 off += (size_t)Bn * Hn * Tn * Nn * 4;   // 640 KB
    float* e_dst = (float*)(ws + off);                 off += (size_t)Bn * Hn * Tn * Nn * 4;   // 640 KB

    if (ws_size < off) {
        k_signal<<<(out_size + 255) / 256, 256, 0, stream>>>(out, out_size);
        return;
    }

    k_transpose_w<<<Hn * (Dn / 64), 256, 0, stream>>>(W, a_src, a_dst, WT);
    k_proj<<<Bn * (Nn / 16), 256, 0, stream>>>(X, WT, hT, e_src, e_dst);
    k_attn<<<Bn * (Nn / 16), 512, 0, stream>>>(adj, e_src, e_dst, hT, bias, gamma, beta, out);
}